// Round 9
// baseline (816.253 us; speedup 1.0000x reference)
//
#include <hip/hip_runtime.h>
#include <hip/hip_bf16.h>

#define D 64
#define BSH 6            // log2(nodes per bucket)
#define BNODES 64
#define NBMAX 2048       // LDS hist capacity (N <= 131072)
#define EB 4096          // edges per hist/fill block

typedef _Float16 f16;
typedef _Float16 f16x4 __attribute__((ext_vector_type(4)));
typedef _Float16 f16x8 __attribute__((ext_vector_type(8)));
typedef float f32x4 __attribute__((ext_vector_type(4)));

__device__ __forceinline__ int sw7(int m, int k) {  // row stride 128 f16
    return (m << 7) + (((k >> 3) ^ (m & 7)) << 3) + (k & 7);
}
__device__ __forceinline__ int sw6(int m, int k) {  // row stride 64 f16
    return (m << 6) + ((((k >> 3) ^ (m & 7)) & 7) << 3) + (k & 7);
}

// ---------------------------------------------------------------------------
// Bucket partition (coarse sort by dst>>6) — two-level LDS histograms.
// ---------------------------------------------------------------------------
__global__ __launch_bounds__(256) void bucket_hist(
    const int* __restrict__ dst, int* __restrict__ bhist, int E, int NB)
{
    __shared__ int lhist[NBMAX];
    int tid = threadIdx.x;
    for (int b = tid; b < NB; b += 256) lhist[b] = 0;
    __syncthreads();
    int base = blockIdx.x * EB;
#pragma unroll
    for (int r = 0; r < EB / 256; ++r) {
        int e = base + r * 256 + tid;
        if (e < E) atomicAdd(&lhist[dst[e] >> BSH], 1);
    }
    __syncthreads();
    for (int b = tid; b < NB; b += 256) {
        int v = lhist[b];
        if (v) atomicAdd(&bhist[b], v);
    }
}

__global__ __launch_bounds__(256) void bucket_scan(
    const int* __restrict__ bhist, int* __restrict__ boff,
    int* __restrict__ bcursor, int NB)
{
    __shared__ int lds[256];
    int tid = threadIdx.x;
    int chunk = (NB + 255) / 256;
    int b0 = tid * chunk;
    int b1 = min(b0 + chunk, NB);
    int s = 0;
    for (int b = b0; b < b1; ++b) s += bhist[b];
    lds[tid] = s;
    __syncthreads();
    for (int d2 = 1; d2 < 256; d2 <<= 1) {
        int v = (tid >= d2) ? lds[tid - d2] : 0;
        __syncthreads();
        lds[tid] += v;
        __syncthreads();
    }
    int run = (tid == 0) ? 0 : lds[tid - 1];
    for (int b = b0; b < b1; ++b) {
        boff[b] = run;
        bcursor[b] = run;
        run += bhist[b];
    }
    if (tid == 255) boff[NB] = lds[255];
}

__global__ __launch_bounds__(256) void bucket_fill(
    const int* __restrict__ dst, const int* __restrict__ src,
    int* __restrict__ bcursor, int2* __restrict__ eix, int E, int NB)
{
    __shared__ int lhist[NBMAX];
    __shared__ int lcur[NBMAX];
    int tid = threadIdx.x;
    for (int b = tid; b < NB; b += 256) lhist[b] = 0;
    __syncthreads();
    int base = blockIdx.x * EB;
    int dv[EB / 256];
#pragma unroll
    for (int r = 0; r < EB / 256; ++r) {
        int e = base + r * 256 + tid;
        dv[r] = (e < E) ? dst[e] : -1;
        if (dv[r] >= 0) atomicAdd(&lhist[dv[r] >> BSH], 1);
    }
    __syncthreads();
    for (int b = tid; b < NB; b += 256) {
        int v = lhist[b];
        lcur[b] = v ? atomicAdd(&bcursor[b], v) : 0;
    }
    __syncthreads();
#pragma unroll
    for (int r = 0; r < EB / 256; ++r) {
        int e = base + r * 256 + tid;
        if (dv[r] >= 0) {
            int p = atomicAdd(&lcur[dv[r] >> BSH], 1);
            eix[p] = make_int2(src[e], dv[r]);
        }
    }
}

// ---------------------------------------------------------------------------
// Per-bucket exact counting sort (64 bins in LDS) -> globally dst-sorted eix2
// + per-node CSR offsets off[]. One block per bucket.
// ---------------------------------------------------------------------------
__global__ __launch_bounds__(256) void bucket_sort(
    const int2* __restrict__ eix, const int* __restrict__ boff,
    int2* __restrict__ eix2, int* __restrict__ off, int N, int NB)
{
    __shared__ int h64[BNODES];
    __shared__ int cur64[BNODES];
    int bk = blockIdx.x;
    int s = boff[bk], e = boff[bk + 1];
    int tid = threadIdx.x;
    int nbase = bk << BSH;

    if (tid < BNODES) h64[tid] = 0;
    __syncthreads();
    for (int i = s + tid; i < e; i += 256)
        atomicAdd(&h64[eix[i].y - nbase], 1);
    __syncthreads();
    if (tid < BNODES) {
        int v = h64[tid];
        int inc = v;
        for (int d2 = 1; d2 < BNODES; d2 <<= 1) {   // wave-level inclusive scan
            int t = __shfl_up(inc, d2);
            if (tid >= d2) inc += t;
        }
        int st = inc - v;                            // exclusive prefix
        cur64[tid] = st;
        int node = nbase + tid;
        if (node < N) off[node] = s + st;
    }
    if (bk == NB - 1 && tid == 0) off[N] = boff[NB]; // = E
    __syncthreads();
    for (int i = s + tid; i < e; i += 256) {
        int2 ed = eix[i];
        int slot = atomicAdd(&cur64[ed.y - nbase], 1);
        eix2[s + slot] = ed;
    }
}

// ---------------------------------------------------------------------------
// Edge MLP via MFMA. Weights in VGPR fragments, A = f16 hi+lo split,
// register gather prefetch, segsum over sorted dst runs.
// Grid 1280 (5 blocks/CU): occupancy was grid-limited at 768 (r8 -> 34%).
// ---------------------------------------------------------------------------
__global__ __launch_bounds__(256, 5) void edge_mfma_kernel(
    const float* __restrict__ x,
    const float* __restrict__ We1, const float* __restrict__ be1,
    const float* __restrict__ We2, const float* __restrict__ be2,
    const int* __restrict__ off, const int2* __restrict__ eix,
    float* __restrict__ hneigh, int N, int E, int T)
{
    __shared__ __attribute__((aligned(16))) f16 Ahi[32 * 128];   // 8KB
    __shared__ __attribute__((aligned(16))) f16 Alo[32 * 128];   // 8KB
    __shared__ __attribute__((aligned(16))) f16 Hbuf[32 * 64];   // 4KB
    __shared__ __attribute__((aligned(16))) float Contrib[32 * 65]; // 8.3KB
    __shared__ int edstS[32];
    __shared__ int offF_, offL_;

    const int tid = threadIdx.x;
    const int w = tid >> 6;
    const int lane = tid & 63;
    const int l15 = lane & 15;
    const int quad = lane >> 4;
    const int m0 = (w & 1) * 16;        // edge strip within tile
    const int nh = (w >> 1) * 32;       // feature half

    f16x8 wb1[4][2];
#pragma unroll
    for (int kt = 0; kt < 4; ++kt)
#pragma unroll
        for (int nf = 0; nf < 2; ++nf) {
            int n = nh + nf * 16 + l15;
#pragma unroll
            for (int j = 0; j < 8; ++j)
                wb1[kt][nf][j] = (f16)We1[(kt * 32 + quad * 8 + j) * 64 + n];
        }
    f16x8 wb2[2][2];
#pragma unroll
    for (int kt = 0; kt < 2; ++kt)
#pragma unroll
        for (int nf = 0; nf < 2; ++nf) {
            int n = nh + nf * 16 + l15;
#pragma unroll
            for (int j = 0; j < 8; ++j)
                wb2[kt][nf][j] = (f16)We2[(kt * 32 + quad * 8 + j) * 64 + n];
        }

    const float b1v0 = be1[nh + l15], b1v1 = be1[nh + 16 + l15];
    const float b2v0 = be2[nh + l15], b2v1 = be2[nh + 16 + l15];

    const int i = tid >> 3;   // staging: edge in tile
    const int c = tid & 7;    // staging: 8-feature chunk

    int2 pe;
    float4 pf0, pf1, pf2, pf3;
    {
        int ei = min(blockIdx.x * 32 + i, E - 1);
        pe = eix[ei];
        const float* ps = x + (size_t)pe.x * D + c * 8;
        const float* pd = x + (size_t)pe.y * D + c * 8;
        pf0 = *(const float4*)ps;
        pf1 = *(const float4*)(ps + 4);
        pf2 = *(const float4*)pd;
        pf3 = *(const float4*)(pd + 4);
    }

    for (int tile = blockIdx.x; tile < T; tile += gridDim.x) {
        const int e0 = tile * 32;
        const int etile = min(32, E - e0);

        {
            float sv[8] = {pf0.x, pf0.y, pf0.z, pf0.w, pf1.x, pf1.y, pf1.z, pf1.w};
            float dv[8] = {pf2.x, pf2.y, pf2.z, pf2.w, pf3.x, pf3.y, pf3.z, pf3.w};
            f16x8 sh, sl, dh, dl;
#pragma unroll
            for (int r = 0; r < 8; ++r) {
                sh[r] = (f16)sv[r]; sl[r] = (f16)(sv[r] - (float)sh[r]);
                dh[r] = (f16)dv[r]; dl[r] = (f16)(dv[r] - (float)dh[r]);
            }
            *(f16x8*)&Ahi[sw7(i, c * 8)] = sh;
            *(f16x8*)&Alo[sw7(i, c * 8)] = sl;
            *(f16x8*)&Ahi[sw7(i, 64 + c * 8)] = dh;
            *(f16x8*)&Alo[sw7(i, 64 + c * 8)] = dl;
            if (c == 0) edstS[i] = (e0 + i < E) ? pe.y : N;
            if (tid == 0)   offF_ = off[pe.y];
            if (tid == 248) offL_ = off[pe.y + 1];
        }
        __syncthreads();  // (1)

        {
            int tn = tile + gridDim.x;
            if (tn < T) {
                int ei = min(tn * 32 + i, E - 1);
                pe = eix[ei];
                const float* ps = x + (size_t)pe.x * D + c * 8;
                const float* pd = x + (size_t)pe.y * D + c * 8;
                pf0 = *(const float4*)ps;
                pf1 = *(const float4*)(ps + 4);
                pf2 = *(const float4*)pd;
                pf3 = *(const float4*)(pd + 4);
            }
        }

        f32x4 c0 = {0.f, 0.f, 0.f, 0.f}, c1 = {0.f, 0.f, 0.f, 0.f};
#pragma unroll
        for (int kt = 0; kt < 4; ++kt) {
            int k = kt * 32 + quad * 8;
            f16x8 ah = *(const f16x8*)&Ahi[sw7(m0 + l15, k)];
            f16x8 al = *(const f16x8*)&Alo[sw7(m0 + l15, k)];
            c0 = __builtin_amdgcn_mfma_f32_16x16x32_f16(ah, wb1[kt][0], c0, 0, 0, 0);
            c0 = __builtin_amdgcn_mfma_f32_16x16x32_f16(al, wb1[kt][0], c0, 0, 0, 0);
            c1 = __builtin_amdgcn_mfma_f32_16x16x32_f16(ah, wb1[kt][1], c1, 0, 0, 0);
            c1 = __builtin_amdgcn_mfma_f32_16x16x32_f16(al, wb1[kt][1], c1, 0, 0, 0);
        }

#pragma unroll
        for (int i2 = 0; i2 < 4; ++i2) {
            int m = m0 + quad * 4 + i2;
            Hbuf[sw6(m, nh + l15)]      = (f16)fmaxf(c0[i2] + b1v0, 0.f);
            Hbuf[sw6(m, nh + 16 + l15)] = (f16)fmaxf(c1[i2] + b1v1, 0.f);
        }
        __syncthreads();  // (2)

        f32x4 d0 = {0.f, 0.f, 0.f, 0.f}, d1 = {0.f, 0.f, 0.f, 0.f};
#pragma unroll
        for (int kt = 0; kt < 2; ++kt) {
            int k = kt * 32 + quad * 8;
            f16x8 ah = *(const f16x8*)&Hbuf[sw6(m0 + l15, k)];
            d0 = __builtin_amdgcn_mfma_f32_16x16x32_f16(ah, wb2[kt][0], d0, 0, 0, 0);
            d1 = __builtin_amdgcn_mfma_f32_16x16x32_f16(ah, wb2[kt][1], d1, 0, 0, 0);
        }

#pragma unroll
        for (int i2 = 0; i2 < 4; ++i2) {
            int m = m0 + quad * 4 + i2;
            float xs0 = (float)Ahi[sw7(m, nh + l15)] + (float)Alo[sw7(m, nh + l15)];
            float xs1 = (float)Ahi[sw7(m, nh + 16 + l15)] + (float)Alo[sw7(m, nh + 16 + l15)];
            Contrib[m * 65 + nh + l15]      = (d0[i2] + b2v0) * xs0;
            Contrib[m * 65 + nh + 16 + l15] = (d1[i2] + b2v1) * xs1;
        }
        __syncthreads();  // (3)

        if (tid < 64) {
            int j = tid;
            float a = 0.f;
            int cur = edstS[0];
            int runStart = 0;
#pragma unroll
            for (int ii = 0; ii < 32; ++ii) {
                a += Contrib[ii * 65 + j];
                int nxt = (ii < 31) ? edstS[ii + 1] : -1;
                if (nxt != cur) {
                    bool isLast = (ii == 31) || (nxt >= N);
                    bool complete = (runStart > 0 || offF_ == e0) &&
                                    (!isLast || offL_ == e0 + etile);
                    if (complete) hneigh[(size_t)cur * D + j] = a;
                    else atomicAdd(&hneigh[(size_t)cur * D + j], a);
                    a = 0.f; cur = nxt; runStart = ii + 1;
                }
            }
        }
        __syncthreads();  // (4)
    }
}

// ---------------------------------------------------------------------------
// Node MLP via MFMA, weights in VGPR fragments, 2-term split.
// ---------------------------------------------------------------------------
__global__ __launch_bounds__(256, 4) void node_mfma_kernel(
    float* __restrict__ h,
    const float* __restrict__ Wn, const float* __restrict__ bn,
    const float* __restrict__ Wg, const float* __restrict__ bg,
    float* __restrict__ gate, int N, int T)
{
    __shared__ __attribute__((aligned(16))) f16 ANhi[64 * 64];
    __shared__ __attribute__((aligned(16))) f16 ANlo[64 * 64];

    const int tid = threadIdx.x;
    const int w = tid >> 6;
    const int lane = tid & 63;
    const int l15 = lane & 15;
    const int quad = lane >> 4;
    const int m0 = w * 16;

    f16x8 wn[2][4];
#pragma unroll
    for (int kt = 0; kt < 2; ++kt)
#pragma unroll
        for (int nf = 0; nf < 4; ++nf) {
            int n = nf * 16 + l15;
#pragma unroll
            for (int j = 0; j < 8; ++j)
                wn[kt][nf][j] = (f16)Wn[(kt * 32 + quad * 8 + j) * 64 + n];
        }

    float bnv[4], wgv[4];
#pragma unroll
    for (int nt = 0; nt < 4; ++nt) {
        bnv[nt] = bn[nt * 16 + l15];
        wgv[nt] = Wg[nt * 16 + l15];
    }
    const float bgv = bg[0];

    for (int tile = blockIdx.x; tile < T; tile += gridDim.x) {
        const int t0 = tile * 64;

        {
            int i = tid >> 2;
            int q = tid & 3;
            int node = min(t0 + i, N - 1);
            const float* p = h + (size_t)node * D + q * 16;
#pragma unroll
            for (int r = 0; r < 4; ++r) {
                float4 v = *(const float4*)(p + r * 4);
                int k = q * 16 + r * 4;
                f16x4 hv, lv;
                hv[0] = (f16)v.x; lv[0] = (f16)(v.x - (float)hv[0]);
                hv[1] = (f16)v.y; lv[1] = (f16)(v.y - (float)hv[1]);
                hv[2] = (f16)v.z; lv[2] = (f16)(v.z - (float)hv[2]);
                hv[3] = (f16)v.w; lv[3] = (f16)(v.w - (float)hv[3]);
                *(f16x4*)&ANhi[sw6(i, k)] = hv;
                *(f16x4*)&ANlo[sw6(i, k)] = lv;
            }
        }
        __syncthreads();

        f32x4 cacc[4] = {{0.f,0.f,0.f,0.f},{0.f,0.f,0.f,0.f},{0.f,0.f,0.f,0.f},{0.f,0.f,0.f,0.f}};
#pragma unroll
        for (int kt = 0; kt < 2; ++kt) {
            int k = kt * 32 + quad * 8;
            f16x8 ah = *(const f16x8*)&ANhi[sw6(m0 + l15, k)];
            f16x8 al = *(const f16x8*)&ANlo[sw6(m0 + l15, k)];
#pragma unroll
            for (int nf = 0; nf < 4; ++nf) {
                cacc[nf] = __builtin_amdgcn_mfma_f32_16x16x32_f16(ah, wn[kt][nf], cacc[nf], 0, 0, 0);
                cacc[nf] = __builtin_amdgcn_mfma_f32_16x16x32_f16(al, wn[kt][nf], cacc[nf], 0, 0, 0);
            }
        }
        __syncthreads();

        float gpart[4] = {0.f, 0.f, 0.f, 0.f};
#pragma unroll
        for (int nt = 0; nt < 4; ++nt) {
            int n = nt * 16 + l15;
#pragma unroll
            for (int i2 = 0; i2 < 4; ++i2) {
                int m = t0 + m0 + quad * 4 + i2;
                float v = fmaxf(cacc[nt][i2] + bnv[nt], 0.f);
                if (m < N) h[(size_t)m * D + n] = v;
                gpart[i2] += v * wgv[nt];
            }
        }
#pragma unroll
        for (int s = 1; s < 16; s <<= 1) {
#pragma unroll
            for (int i2 = 0; i2 < 4; ++i2) gpart[i2] += __shfl_xor(gpart[i2], s);
        }
        if (l15 == 0) {
#pragma unroll
            for (int i2 = 0; i2 < 4; ++i2) {
                int m = t0 + m0 + quad * 4 + i2;
                if (m < N) gate[m] = gpart[i2] + bgv;
            }
        }
    }
}

// ---------------------------------------------------------------------------
// Pool: one block per graph; softmax over gates, weighted sum, classifier.
// ---------------------------------------------------------------------------
__global__ __launch_bounds__(256) void pool_kernel(
    const float* __restrict__ h2,
    const float* __restrict__ gate,
    const int* __restrict__ gid,
    const float* __restrict__ Wfc, const float* __restrict__ bfc,
    float* __restrict__ out, int N, int C)
{
    int g = blockIdx.x;
    int tid = threadIdx.x;

    int lo = 0, hi = N;
    while (lo < hi) { int mid = (lo + hi) >> 1; if (gid[mid] < g) lo = mid + 1; else hi = mid; }
    int s = lo;
    hi = N;
    while (lo < hi) { int mid = (lo + hi) >> 1; if (gid[mid] < g + 1) lo = mid + 1; else hi = mid; }
    int e = lo;

    __shared__ float red[256];
    __shared__ float accs[4][D];
    __shared__ float dens[4];

    float m = -INFINITY;
    for (int i = s + tid; i < e; i += 256) m = fmaxf(m, gate[i]);
    red[tid] = m;
    __syncthreads();
    for (int w = 128; w > 0; w >>= 1) {
        if (tid < w) red[tid] = fmaxf(red[tid], red[tid + w]);
        __syncthreads();
    }
    float gmax = red[0];
    __syncthreads();

    int f = tid & (D - 1);
    int grp = tid >> 6;
    float acc = 0.0f, den = 0.0f;
    for (int i = s + grp; i < e; i += 4) {
        float w = expf(gate[i] - gmax);
        acc += w * h2[(size_t)i * D + f];
        if (f == 0) den += w;
    }
    accs[grp][f] = acc;
    if (f == 0) dens[grp] = den;
    __syncthreads();

    if (tid < D) {
        float p = accs[0][tid] + accs[1][tid] + accs[2][tid] + accs[3][tid];
        float dn = dens[0] + dens[1] + dens[2] + dens[3];
        p = (e > s) ? (p / dn) : 0.0f;
        red[tid] = p;
    }
    __syncthreads();

    if (tid < C) {
        float o = bfc[tid];
#pragma unroll
        for (int k = 0; k < D; ++k) o += red[k] * Wfc[k * C + tid];
        out[g * C + tid] = o;
    }
}

extern "C" void kernel_launch(void* const* d_in, const int* in_sizes, int n_in,
                              void* d_out, int out_size, void* d_ws, size_t ws_size,
                              hipStream_t stream) {
    const float* x   = (const float*)d_in[0];
    const float* We1 = (const float*)d_in[1];
    const float* be1 = (const float*)d_in[2];
    const float* We2 = (const float*)d_in[3];
    const float* be2 = (const float*)d_in[4];
    const float* Wn  = (const float*)d_in[5];
    const float* bn  = (const float*)d_in[6];
    const float* Wg  = (const float*)d_in[7];
    const float* bg  = (const float*)d_in[8];
    const float* Wfc = (const float*)d_in[9];
    const float* bfc = (const float*)d_in[10];
    const int* src = (const int*)d_in[11];
    const int* dst = (const int*)d_in[12];
    const int* gid = (const int*)d_in[13];

    const int N = in_sizes[0] / D;
    const int E = in_sizes[11];
    const int C = 10;
    const int G = out_size / C;
    const int NB = (N + BNODES - 1) / BNODES;

    // workspace: eix2 | union{eixA, hneigh} | gate | off | bucket arrays
    int2*  eix2   = (int2*)d_ws;                          // [E]      12.8MB
    int2*  eixA   = eix2 + E;                             // [E]      12.8MB
    float* hneigh = (float*)eixA;                         // [(N+1)*64] 25.6MB (overlay)
    float* gate   = hneigh + (size_t)(N + 1) * D;         // [N]
    int*   off    = (int*)(gate + N);                     // [N+1]
    int*   bhist  = off + N + 1;                          // [NB]
    int*   boff   = bhist + NB;                           // [NB+1]
    int*   bcursor= boff + NB + 1;                        // [NB]
    float* outp   = (float*)d_out;

    const int Bh = (E + EB - 1) / EB;
    const int Te = (E + 31) / 32;
    const int Tn = (N + 63) / 64;

    hipMemsetAsync(bhist, 0, (size_t)NB * sizeof(int), stream);

    bucket_hist<<<Bh, 256, 0, stream>>>(dst, bhist, E, NB);
    bucket_scan<<<1, 256, 0, stream>>>(bhist, boff, bcursor, NB);
    bucket_fill<<<Bh, 256, 0, stream>>>(dst, src, bcursor, eixA, E, NB);
    bucket_sort<<<NB, 256, 0, stream>>>(eixA, boff, eix2, off, N, NB);

    // eixA dead; zero hneigh (overlay) before edge kernel
    hipMemsetAsync(hneigh, 0, (size_t)(N + 1) * D * sizeof(float), stream);

    edge_mfma_kernel<<<1280, 256, 0, stream>>>(x, We1, be1, We2, be2,
                                               off, eix2, hneigh, N, E, Te);
    node_mfma_kernel<<<1024, 256, 0, stream>>>(hneigh, Wn, bn, Wg, bg, gate, N, Tn);
    pool_kernel<<<G, 256, 0, stream>>>(hneigh, gate, gid, Wfc, bfc, outp, N, C);
}

// Round 10
// 558.305 us; speedup vs baseline: 1.4620x; 1.4620x over previous
//
#include <hip/hip_runtime.h>
#include <hip/hip_bf16.h>

#define D 64
#define BSH 6            // log2(nodes per bucket)
#define BNODES 64
#define NBMAX 2048       // LDS hist capacity (N <= 131072)
#define EB 4096          // edges per hist/fill block

typedef _Float16 f16;
typedef _Float16 f16x4 __attribute__((ext_vector_type(4)));
typedef _Float16 f16x8 __attribute__((ext_vector_type(8)));
typedef float f32x4 __attribute__((ext_vector_type(4)));

__device__ __forceinline__ int sw7(int m, int k) {  // row stride 128 f16
    return (m << 7) + (((k >> 3) ^ (m & 7)) << 3) + (k & 7);
}
__device__ __forceinline__ int sw6(int m, int k) {  // row stride 64 f16
    return (m << 6) + ((((k >> 3) ^ (m & 7)) & 7) << 3) + (k & 7);
}

// ---------------------------------------------------------------------------
// Bucket partition (coarse sort by dst>>6) — two-level LDS histograms.
// ---------------------------------------------------------------------------
__global__ __launch_bounds__(256) void bucket_hist(
    const int* __restrict__ dst, int* __restrict__ bhist, int E, int NB)
{
    __shared__ int lhist[NBMAX];
    int tid = threadIdx.x;
    for (int b = tid; b < NB; b += 256) lhist[b] = 0;
    __syncthreads();
    int base = blockIdx.x * EB;
#pragma unroll
    for (int r = 0; r < EB / 256; ++r) {
        int e = base + r * 256 + tid;
        if (e < E) atomicAdd(&lhist[dst[e] >> BSH], 1);
    }
    __syncthreads();
    for (int b = tid; b < NB; b += 256) {
        int v = lhist[b];
        if (v) atomicAdd(&bhist[b], v);
    }
}

__global__ __launch_bounds__(256) void bucket_scan(
    const int* __restrict__ bhist, int* __restrict__ boff,
    int* __restrict__ bcursor, int NB)
{
    __shared__ int lds[256];
    int tid = threadIdx.x;
    int chunk = (NB + 255) / 256;
    int b0 = tid * chunk;
    int b1 = min(b0 + chunk, NB);
    int s = 0;
    for (int b = b0; b < b1; ++b) s += bhist[b];
    lds[tid] = s;
    __syncthreads();
    for (int d2 = 1; d2 < 256; d2 <<= 1) {
        int v = (tid >= d2) ? lds[tid - d2] : 0;
        __syncthreads();
        lds[tid] += v;
        __syncthreads();
    }
    int run = (tid == 0) ? 0 : lds[tid - 1];
    for (int b = b0; b < b1; ++b) {
        boff[b] = run;
        bcursor[b] = run;
        run += bhist[b];
    }
    if (tid == 255) boff[NB] = lds[255];
}

__global__ __launch_bounds__(256) void bucket_fill(
    const int* __restrict__ dst, const int* __restrict__ src,
    int* __restrict__ bcursor, int2* __restrict__ eix, int E, int NB)
{
    __shared__ int lhist[NBMAX];
    __shared__ int lcur[NBMAX];
    int tid = threadIdx.x;
    for (int b = tid; b < NB; b += 256) lhist[b] = 0;
    __syncthreads();
    int base = blockIdx.x * EB;
    int dv[EB / 256];
#pragma unroll
    for (int r = 0; r < EB / 256; ++r) {
        int e = base + r * 256 + tid;
        dv[r] = (e < E) ? dst[e] : -1;
        if (dv[r] >= 0) atomicAdd(&lhist[dv[r] >> BSH], 1);
    }
    __syncthreads();
    for (int b = tid; b < NB; b += 256) {
        int v = lhist[b];
        lcur[b] = v ? atomicAdd(&bcursor[b], v) : 0;
    }
    __syncthreads();
#pragma unroll
    for (int r = 0; r < EB / 256; ++r) {
        int e = base + r * 256 + tid;
        if (dv[r] >= 0) {
            int p = atomicAdd(&lcur[dv[r] >> BSH], 1);
            eix[p] = make_int2(src[e], dv[r]);
        }
    }
}

// ---------------------------------------------------------------------------
// Per-bucket exact counting sort (64 bins in LDS) -> globally dst-sorted eix2
// + per-node CSR offsets off[]. One block per bucket.
// ---------------------------------------------------------------------------
__global__ __launch_bounds__(256) void bucket_sort(
    const int2* __restrict__ eix, const int* __restrict__ boff,
    int2* __restrict__ eix2, int* __restrict__ off, int N, int NB)
{
    __shared__ int h64[BNODES];
    __shared__ int cur64[BNODES];
    int bk = blockIdx.x;
    int s = boff[bk], e = boff[bk + 1];
    int tid = threadIdx.x;
    int nbase = bk << BSH;

    if (tid < BNODES) h64[tid] = 0;
    __syncthreads();
    for (int i = s + tid; i < e; i += 256)
        atomicAdd(&h64[eix[i].y - nbase], 1);
    __syncthreads();
    if (tid < BNODES) {
        int v = h64[tid];
        int inc = v;
        for (int d2 = 1; d2 < BNODES; d2 <<= 1) {   // wave-level inclusive scan
            int t = __shfl_up(inc, d2);
            if (tid >= d2) inc += t;
        }
        int st = inc - v;                            // exclusive prefix
        cur64[tid] = st;
        int node = nbase + tid;
        if (node < N) off[node] = s + st;
    }
    if (bk == NB - 1 && tid == 0) off[N] = boff[NB]; // = E
    __syncthreads();
    for (int i = s + tid; i < e; i += 256) {
        int2 ed = eix[i];
        int slot = atomicAdd(&cur64[ed.y - nbase], 1);
        eix2[s + slot] = ed;
    }
}

// ---------------------------------------------------------------------------
// Edge MLP via MFMA. Weights in VGPR fragments, A = f16 hi+lo split,
// register gather prefetch, segsum over sorted dst runs.
// launch_bounds (256,3): (256,5) at r9 capped VGPR to 48 -> weight-fragment
// spill to scratch -> FETCH 194MB->1.33GB. VGPR=76 natively allows 6 w/SIMD;
// LDS 29.2KB allows 5 blocks/CU; grid 1280 = 5/CU provides the residency.
// ---------------------------------------------------------------------------
__global__ __launch_bounds__(256, 3) void edge_mfma_kernel(
    const float* __restrict__ x,
    const float* __restrict__ We1, const float* __restrict__ be1,
    const float* __restrict__ We2, const float* __restrict__ be2,
    const int* __restrict__ off, const int2* __restrict__ eix,
    float* __restrict__ hneigh, int N, int E, int T)
{
    __shared__ __attribute__((aligned(16))) f16 Ahi[32 * 128];   // 8KB
    __shared__ __attribute__((aligned(16))) f16 Alo[32 * 128];   // 8KB
    __shared__ __attribute__((aligned(16))) f16 Hbuf[32 * 64];   // 4KB
    __shared__ __attribute__((aligned(16))) float Contrib[32 * 65]; // 8.3KB
    __shared__ int edstS[32];
    __shared__ int offF_, offL_;

    const int tid = threadIdx.x;
    const int w = tid >> 6;
    const int lane = tid & 63;
    const int l15 = lane & 15;
    const int quad = lane >> 4;
    const int m0 = (w & 1) * 16;        // edge strip within tile
    const int nh = (w >> 1) * 32;       // feature half

    f16x8 wb1[4][2];
#pragma unroll
    for (int kt = 0; kt < 4; ++kt)
#pragma unroll
        for (int nf = 0; nf < 2; ++nf) {
            int n = nh + nf * 16 + l15;
#pragma unroll
            for (int j = 0; j < 8; ++j)
                wb1[kt][nf][j] = (f16)We1[(kt * 32 + quad * 8 + j) * 64 + n];
        }
    f16x8 wb2[2][2];
#pragma unroll
    for (int kt = 0; kt < 2; ++kt)
#pragma unroll
        for (int nf = 0; nf < 2; ++nf) {
            int n = nh + nf * 16 + l15;
#pragma unroll
            for (int j = 0; j < 8; ++j)
                wb2[kt][nf][j] = (f16)We2[(kt * 32 + quad * 8 + j) * 64 + n];
        }

    const float b1v0 = be1[nh + l15], b1v1 = be1[nh + 16 + l15];
    const float b2v0 = be2[nh + l15], b2v1 = be2[nh + 16 + l15];

    const int i = tid >> 3;   // staging: edge in tile
    const int c = tid & 7;    // staging: 8-feature chunk

    int2 pe;
    float4 pf0, pf1, pf2, pf3;
    {
        int ei = min(blockIdx.x * 32 + i, E - 1);
        pe = eix[ei];
        const float* ps = x + (size_t)pe.x * D + c * 8;
        const float* pd = x + (size_t)pe.y * D + c * 8;
        pf0 = *(const float4*)ps;
        pf1 = *(const float4*)(ps + 4);
        pf2 = *(const float4*)pd;
        pf3 = *(const float4*)(pd + 4);
    }

    for (int tile = blockIdx.x; tile < T; tile += gridDim.x) {
        const int e0 = tile * 32;
        const int etile = min(32, E - e0);

        {
            float sv[8] = {pf0.x, pf0.y, pf0.z, pf0.w, pf1.x, pf1.y, pf1.z, pf1.w};
            float dv[8] = {pf2.x, pf2.y, pf2.z, pf2.w, pf3.x, pf3.y, pf3.z, pf3.w};
            f16x8 sh, sl, dh, dl;
#pragma unroll
            for (int r = 0; r < 8; ++r) {
                sh[r] = (f16)sv[r]; sl[r] = (f16)(sv[r] - (float)sh[r]);
                dh[r] = (f16)dv[r]; dl[r] = (f16)(dv[r] - (float)dh[r]);
            }
            *(f16x8*)&Ahi[sw7(i, c * 8)] = sh;
            *(f16x8*)&Alo[sw7(i, c * 8)] = sl;
            *(f16x8*)&Ahi[sw7(i, 64 + c * 8)] = dh;
            *(f16x8*)&Alo[sw7(i, 64 + c * 8)] = dl;
            if (c == 0) edstS[i] = (e0 + i < E) ? pe.y : N;
            if (tid == 0)   offF_ = off[pe.y];
            if (tid == 248) offL_ = off[pe.y + 1];
        }
        __syncthreads();  // (1)

        {
            int tn = tile + gridDim.x;
            if (tn < T) {
                int ei = min(tn * 32 + i, E - 1);
                pe = eix[ei];
                const float* ps = x + (size_t)pe.x * D + c * 8;
                const float* pd = x + (size_t)pe.y * D + c * 8;
                pf0 = *(const float4*)ps;
                pf1 = *(const float4*)(ps + 4);
                pf2 = *(const float4*)pd;
                pf3 = *(const float4*)(pd + 4);
            }
        }

        f32x4 c0 = {0.f, 0.f, 0.f, 0.f}, c1 = {0.f, 0.f, 0.f, 0.f};
#pragma unroll
        for (int kt = 0; kt < 4; ++kt) {
            int k = kt * 32 + quad * 8;
            f16x8 ah = *(const f16x8*)&Ahi[sw7(m0 + l15, k)];
            f16x8 al = *(const f16x8*)&Alo[sw7(m0 + l15, k)];
            c0 = __builtin_amdgcn_mfma_f32_16x16x32_f16(ah, wb1[kt][0], c0, 0, 0, 0);
            c0 = __builtin_amdgcn_mfma_f32_16x16x32_f16(al, wb1[kt][0], c0, 0, 0, 0);
            c1 = __builtin_amdgcn_mfma_f32_16x16x32_f16(ah, wb1[kt][1], c1, 0, 0, 0);
            c1 = __builtin_amdgcn_mfma_f32_16x16x32_f16(al, wb1[kt][1], c1, 0, 0, 0);
        }

#pragma unroll
        for (int i2 = 0; i2 < 4; ++i2) {
            int m = m0 + quad * 4 + i2;
            Hbuf[sw6(m, nh + l15)]      = (f16)fmaxf(c0[i2] + b1v0, 0.f);
            Hbuf[sw6(m, nh + 16 + l15)] = (f16)fmaxf(c1[i2] + b1v1, 0.f);
        }
        __syncthreads();  // (2)

        f32x4 d0 = {0.f, 0.f, 0.f, 0.f}, d1 = {0.f, 0.f, 0.f, 0.f};
#pragma unroll
        for (int kt = 0; kt < 2; ++kt) {
            int k = kt * 32 + quad * 8;
            f16x8 ah = *(const f16x8*)&Hbuf[sw6(m0 + l15, k)];
            d0 = __builtin_amdgcn_mfma_f32_16x16x32_f16(ah, wb2[kt][0], d0, 0, 0, 0);
            d1 = __builtin_amdgcn_mfma_f32_16x16x32_f16(ah, wb2[kt][1], d1, 0, 0, 0);
        }

#pragma unroll
        for (int i2 = 0; i2 < 4; ++i2) {
            int m = m0 + quad * 4 + i2;
            float xs0 = (float)Ahi[sw7(m, nh + l15)] + (float)Alo[sw7(m, nh + l15)];
            float xs1 = (float)Ahi[sw7(m, nh + 16 + l15)] + (float)Alo[sw7(m, nh + 16 + l15)];
            Contrib[m * 65 + nh + l15]      = (d0[i2] + b2v0) * xs0;
            Contrib[m * 65 + nh + 16 + l15] = (d1[i2] + b2v1) * xs1;
        }
        __syncthreads();  // (3)

        if (tid < 64) {
            int j = tid;
            float a = 0.f;
            int cur = edstS[0];
            int runStart = 0;
#pragma unroll
            for (int ii = 0; ii < 32; ++ii) {
                a += Contrib[ii * 65 + j];
                int nxt = (ii < 31) ? edstS[ii + 1] : -1;
                if (nxt != cur) {
                    bool isLast = (ii == 31) || (nxt >= N);
                    bool complete = (runStart > 0 || offF_ == e0) &&
                                    (!isLast || offL_ == e0 + etile);
                    if (complete) hneigh[(size_t)cur * D + j] = a;
                    else atomicAdd(&hneigh[(size_t)cur * D + j], a);
                    a = 0.f; cur = nxt; runStart = ii + 1;
                }
            }
        }
        __syncthreads();  // (4)
    }
}

// ---------------------------------------------------------------------------
// Node MLP via MFMA, weights in VGPR fragments, 2-term split.
// ---------------------------------------------------------------------------
__global__ __launch_bounds__(256, 4) void node_mfma_kernel(
    float* __restrict__ h,
    const float* __restrict__ Wn, const float* __restrict__ bn,
    const float* __restrict__ Wg, const float* __restrict__ bg,
    float* __restrict__ gate, int N, int T)
{
    __shared__ __attribute__((aligned(16))) f16 ANhi[64 * 64];
    __shared__ __attribute__((aligned(16))) f16 ANlo[64 * 64];

    const int tid = threadIdx.x;
    const int w = tid >> 6;
    const int lane = tid & 63;
    const int l15 = lane & 15;
    const int quad = lane >> 4;
    const int m0 = w * 16;

    f16x8 wn[2][4];
#pragma unroll
    for (int kt = 0; kt < 2; ++kt)
#pragma unroll
        for (int nf = 0; nf < 4; ++nf) {
            int n = nf * 16 + l15;
#pragma unroll
            for (int j = 0; j < 8; ++j)
                wn[kt][nf][j] = (f16)Wn[(kt * 32 + quad * 8 + j) * 64 + n];
        }

    float bnv[4], wgv[4];
#pragma unroll
    for (int nt = 0; nt < 4; ++nt) {
        bnv[nt] = bn[nt * 16 + l15];
        wgv[nt] = Wg[nt * 16 + l15];
    }
    const float bgv = bg[0];

    for (int tile = blockIdx.x; tile < T; tile += gridDim.x) {
        const int t0 = tile * 64;

        {
            int i = tid >> 2;
            int q = tid & 3;
            int node = min(t0 + i, N - 1);
            const float* p = h + (size_t)node * D + q * 16;
#pragma unroll
            for (int r = 0; r < 4; ++r) {
                float4 v = *(const float4*)(p + r * 4);
                int k = q * 16 + r * 4;
                f16x4 hv, lv;
                hv[0] = (f16)v.x; lv[0] = (f16)(v.x - (float)hv[0]);
                hv[1] = (f16)v.y; lv[1] = (f16)(v.y - (float)hv[1]);
                hv[2] = (f16)v.z; lv[2] = (f16)(v.z - (float)hv[2]);
                hv[3] = (f16)v.w; lv[3] = (f16)(v.w - (float)hv[3]);
                *(f16x4*)&ANhi[sw6(i, k)] = hv;
                *(f16x4*)&ANlo[sw6(i, k)] = lv;
            }
        }
        __syncthreads();

        f32x4 cacc[4] = {{0.f,0.f,0.f,0.f},{0.f,0.f,0.f,0.f},{0.f,0.f,0.f,0.f},{0.f,0.f,0.f,0.f}};
#pragma unroll
        for (int kt = 0; kt < 2; ++kt) {
            int k = kt * 32 + quad * 8;
            f16x8 ah = *(const f16x8*)&ANhi[sw6(m0 + l15, k)];
            f16x8 al = *(const f16x8*)&ANlo[sw6(m0 + l15, k)];
#pragma unroll
            for (int nf = 0; nf < 4; ++nf) {
                cacc[nf] = __builtin_amdgcn_mfma_f32_16x16x32_f16(ah, wn[kt][nf], cacc[nf], 0, 0, 0);
                cacc[nf] = __builtin_amdgcn_mfma_f32_16x16x32_f16(al, wn[kt][nf], cacc[nf], 0, 0, 0);
            }
        }
        __syncthreads();

        float gpart[4] = {0.f, 0.f, 0.f, 0.f};
#pragma unroll
        for (int nt = 0; nt < 4; ++nt) {
            int n = nt * 16 + l15;
#pragma unroll
            for (int i2 = 0; i2 < 4; ++i2) {
                int m = t0 + m0 + quad * 4 + i2;
                float v = fmaxf(cacc[nt][i2] + bnv[nt], 0.f);
                if (m < N) h[(size_t)m * D + n] = v;
                gpart[i2] += v * wgv[nt];
            }
        }
#pragma unroll
        for (int s = 1; s < 16; s <<= 1) {
#pragma unroll
            for (int i2 = 0; i2 < 4; ++i2) gpart[i2] += __shfl_xor(gpart[i2], s);
        }
        if (l15 == 0) {
#pragma unroll
            for (int i2 = 0; i2 < 4; ++i2) {
                int m = t0 + m0 + quad * 4 + i2;
                if (m < N) gate[m] = gpart[i2] + bgv;
            }
        }
    }
}

// ---------------------------------------------------------------------------
// Pool: one block per graph; softmax over gates, weighted sum, classifier.
// ---------------------------------------------------------------------------
__global__ __launch_bounds__(256) void pool_kernel(
    const float* __restrict__ h2,
    const float* __restrict__ gate,
    const int* __restrict__ gid,
    const float* __restrict__ Wfc, const float* __restrict__ bfc,
    float* __restrict__ out, int N, int C)
{
    int g = blockIdx.x;
    int tid = threadIdx.x;

    int lo = 0, hi = N;
    while (lo < hi) { int mid = (lo + hi) >> 1; if (gid[mid] < g) lo = mid + 1; else hi = mid; }
    int s = lo;
    hi = N;
    while (lo < hi) { int mid = (lo + hi) >> 1; if (gid[mid] < g + 1) lo = mid + 1; else hi = mid; }
    int e = lo;

    __shared__ float red[256];
    __shared__ float accs[4][D];
    __shared__ float dens[4];

    float m = -INFINITY;
    for (int i = s + tid; i < e; i += 256) m = fmaxf(m, gate[i]);
    red[tid] = m;
    __syncthreads();
    for (int w = 128; w > 0; w >>= 1) {
        if (tid < w) red[tid] = fmaxf(red[tid], red[tid + w]);
        __syncthreads();
    }
    float gmax = red[0];
    __syncthreads();

    int f = tid & (D - 1);
    int grp = tid >> 6;
    float acc = 0.0f, den = 0.0f;
    for (int i = s + grp; i < e; i += 4) {
        float w = expf(gate[i] - gmax);
        acc += w * h2[(size_t)i * D + f];
        if (f == 0) den += w;
    }
    accs[grp][f] = acc;
    if (f == 0) dens[grp] = den;
    __syncthreads();

    if (tid < D) {
        float p = accs[0][tid] + accs[1][tid] + accs[2][tid] + accs[3][tid];
        float dn = dens[0] + dens[1] + dens[2] + dens[3];
        p = (e > s) ? (p / dn) : 0.0f;
        red[tid] = p;
    }
    __syncthreads();

    if (tid < C) {
        float o = bfc[tid];
#pragma unroll
        for (int k = 0; k < D; ++k) o += red[k] * Wfc[k * C + tid];
        out[g * C + tid] = o;
    }
}

extern "C" void kernel_launch(void* const* d_in, const int* in_sizes, int n_in,
                              void* d_out, int out_size, void* d_ws, size_t ws_size,
                              hipStream_t stream) {
    const float* x   = (const float*)d_in[0];
    const float* We1 = (const float*)d_in[1];
    const float* be1 = (const float*)d_in[2];
    const float* We2 = (const float*)d_in[3];
    const float* be2 = (const float*)d_in[4];
    const float* Wn  = (const float*)d_in[5];
    const float* bn  = (const float*)d_in[6];
    const float* Wg  = (const float*)d_in[7];
    const float* bg  = (const float*)d_in[8];
    const float* Wfc = (const float*)d_in[9];
    const float* bfc = (const float*)d_in[10];
    const int* src = (const int*)d_in[11];
    const int* dst = (const int*)d_in[12];
    const int* gid = (const int*)d_in[13];

    const int N = in_sizes[0] / D;
    const int E = in_sizes[11];
    const int C = 10;
    const int G = out_size / C;
    const int NB = (N + BNODES - 1) / BNODES;

    // workspace: eix2 | union{eixA, hneigh} | gate | off | bucket arrays
    int2*  eix2   = (int2*)d_ws;                          // [E]      12.8MB
    int2*  eixA   = eix2 + E;                             // [E]      12.8MB
    float* hneigh = (float*)eixA;                         // [(N+1)*64] 25.6MB (overlay)
    float* gate   = hneigh + (size_t)(N + 1) * D;         // [N]
    int*   off    = (int*)(gate + N);                     // [N+1]
    int*   bhist  = off + N + 1;                          // [NB]
    int*   boff   = bhist + NB;                           // [NB+1]
    int*   bcursor= boff + NB + 1;                        // [NB]
    float* outp   = (float*)d_out;

    const int Bh = (E + EB - 1) / EB;
    const int Te = (E + 31) / 32;
    const int Tn = (N + 63) / 64;

    hipMemsetAsync(bhist, 0, (size_t)NB * sizeof(int), stream);

    bucket_hist<<<Bh, 256, 0, stream>>>(dst, bhist, E, NB);
    bucket_scan<<<1, 256, 0, stream>>>(bhist, boff, bcursor, NB);
    bucket_fill<<<Bh, 256, 0, stream>>>(dst, src, bcursor, eixA, E, NB);
    bucket_sort<<<NB, 256, 0, stream>>>(eixA, boff, eix2, off, N, NB);

    // eixA dead; zero hneigh (overlay) before edge kernel
    hipMemsetAsync(hneigh, 0, (size_t)(N + 1) * D * sizeof(float), stream);

    edge_mfma_kernel<<<1280, 256, 0, stream>>>(x, We1, be1, We2, be2,
                                               off, eix2, hneigh, N, E, Te);
    node_mfma_kernel<<<1024, 256, 0, stream>>>(hneigh, Wn, bn, Wg, bg, gate, N, Tn);
    pool_kernel<<<G, 256, 0, stream>>>(hneigh, gate, gid, Wfc, bfc, outp, N, C);
}

// Round 11
// 452.215 us; speedup vs baseline: 1.8050x; 1.2346x over previous
//
#include <hip/hip_runtime.h>
#include <hip/hip_bf16.h>

#define D 64
#define BSH 6            // log2(nodes per bucket)
#define BNODES 64
#define NBMAX 2048       // LDS hist capacity (N <= 131072)
#define EB 4096          // edges per hist/fill block

typedef _Float16 f16;
typedef _Float16 f16x4 __attribute__((ext_vector_type(4)));
typedef _Float16 f16x8 __attribute__((ext_vector_type(8)));
typedef float f32x4 __attribute__((ext_vector_type(4)));

__device__ __forceinline__ int sw7(int m, int k) {  // row stride 128 f16
    return (m << 7) + (((k >> 3) ^ (m & 7)) << 3) + (k & 7);
}
__device__ __forceinline__ int sw6(int m, int k) {  // row stride 64 f16
    return (m << 6) + ((((k >> 3) ^ (m & 7)) & 7) << 3) + (k & 7);
}

// ---------------------------------------------------------------------------
// Bucket partition (coarse sort by dst>>6) — two-level LDS histograms.
// ---------------------------------------------------------------------------
__global__ __launch_bounds__(256) void bucket_hist(
    const int* __restrict__ dst, int* __restrict__ bhist, int E, int NB)
{
    __shared__ int lhist[NBMAX];
    int tid = threadIdx.x;
    for (int b = tid; b < NB; b += 256) lhist[b] = 0;
    __syncthreads();
    int base = blockIdx.x * EB;
#pragma unroll
    for (int r = 0; r < EB / 256; ++r) {
        int e = base + r * 256 + tid;
        if (e < E) atomicAdd(&lhist[dst[e] >> BSH], 1);
    }
    __syncthreads();
    for (int b = tid; b < NB; b += 256) {
        int v = lhist[b];
        if (v) atomicAdd(&bhist[b], v);
    }
}

__global__ __launch_bounds__(256) void bucket_scan(
    const int* __restrict__ bhist, int* __restrict__ boff,
    int* __restrict__ bcursor, int NB)
{
    __shared__ int lds[256];
    int tid = threadIdx.x;
    int chunk = (NB + 255) / 256;
    int b0 = tid * chunk;
    int b1 = min(b0 + chunk, NB);
    int s = 0;
    for (int b = b0; b < b1; ++b) s += bhist[b];
    lds[tid] = s;
    __syncthreads();
    for (int d2 = 1; d2 < 256; d2 <<= 1) {
        int v = (tid >= d2) ? lds[tid - d2] : 0;
        __syncthreads();
        lds[tid] += v;
        __syncthreads();
    }
    int run = (tid == 0) ? 0 : lds[tid - 1];
    for (int b = b0; b < b1; ++b) {
        boff[b] = run;
        bcursor[b] = run;
        run += bhist[b];
    }
    if (tid == 255) boff[NB] = lds[255];
}

__global__ __launch_bounds__(256) void bucket_fill(
    const int* __restrict__ dst, const int* __restrict__ src,
    int* __restrict__ bcursor, int2* __restrict__ eix, int E, int NB)
{
    __shared__ int lhist[NBMAX];
    __shared__ int lcur[NBMAX];
    int tid = threadIdx.x;
    for (int b = tid; b < NB; b += 256) lhist[b] = 0;
    __syncthreads();
    int base = blockIdx.x * EB;
    int dv[EB / 256];
#pragma unroll
    for (int r = 0; r < EB / 256; ++r) {
        int e = base + r * 256 + tid;
        dv[r] = (e < E) ? dst[e] : -1;
        if (dv[r] >= 0) atomicAdd(&lhist[dv[r] >> BSH], 1);
    }
    __syncthreads();
    for (int b = tid; b < NB; b += 256) {
        int v = lhist[b];
        lcur[b] = v ? atomicAdd(&bcursor[b], v) : 0;
    }
    __syncthreads();
#pragma unroll
    for (int r = 0; r < EB / 256; ++r) {
        int e = base + r * 256 + tid;
        if (dv[r] >= 0) {
            int p = atomicAdd(&lcur[dv[r] >> BSH], 1);
            eix[p] = make_int2(src[e], dv[r]);
        }
    }
}

// ---------------------------------------------------------------------------
// Per-bucket exact counting sort (64 bins in LDS) -> globally dst-sorted eix2
// + per-node CSR offsets off[]. One block per bucket.
// ---------------------------------------------------------------------------
__global__ __launch_bounds__(256) void bucket_sort(
    const int2* __restrict__ eix, const int* __restrict__ boff,
    int2* __restrict__ eix2, int* __restrict__ off, int N, int NB)
{
    __shared__ int h64[BNODES];
    __shared__ int cur64[BNODES];
    int bk = blockIdx.x;
    int s = boff[bk], e = boff[bk + 1];
    int tid = threadIdx.x;
    int nbase = bk << BSH;

    if (tid < BNODES) h64[tid] = 0;
    __syncthreads();
    for (int i = s + tid; i < e; i += 256)
        atomicAdd(&h64[eix[i].y - nbase], 1);
    __syncthreads();
    if (tid < BNODES) {
        int v = h64[tid];
        int inc = v;
        for (int d2 = 1; d2 < BNODES; d2 <<= 1) {   // wave-level inclusive scan
            int t = __shfl_up(inc, d2);
            if (tid >= d2) inc += t;
        }
        int st = inc - v;                            // exclusive prefix
        cur64[tid] = st;
        int node = nbase + tid;
        if (node < N) off[node] = s + st;
    }
    if (bk == NB - 1 && tid == 0) off[N] = boff[NB]; // = E
    __syncthreads();
    for (int i = s + tid; i < e; i += 256) {
        int2 ed = eix[i];
        int slot = atomicAdd(&cur64[ed.y - nbase], 1);
        eix2[s + slot] = ed;
    }
}

// ---------------------------------------------------------------------------
// Edge MLP via MFMA. wb1 in VGPR fragments; We2 in LDS (register budget:
// unified VGPR+AGPR must stay <=128/wave for 4 blocks/CU — r10 showed the
// r8 config was register-limited to 3 blocks/CU at ~140 unified regs).
// dst-row prefetch dropped: sorted order makes xd L1-hot (~2 rows/tile).
// Grid 1024 = 4 blocks/CU exactly.
// ---------------------------------------------------------------------------
__global__ __launch_bounds__(256, 4) void edge_mfma_kernel(
    const float* __restrict__ x,
    const float* __restrict__ We1, const float* __restrict__ be1,
    const float* __restrict__ We2, const float* __restrict__ be2,
    const int* __restrict__ off, const int2* __restrict__ eix,
    float* __restrict__ hneigh, int N, int E, int T)
{
    __shared__ __attribute__((aligned(16))) f16 Ahi[32 * 128];   // 8KB
    __shared__ __attribute__((aligned(16))) f16 Alo[32 * 128];   // 8KB
    __shared__ __attribute__((aligned(16))) f16 Hbuf[32 * 64];   // 4KB
    __shared__ __attribute__((aligned(16))) f16 W2s[64 * 64];    // 8KB
    __shared__ __attribute__((aligned(16))) float Contrib[32 * 65]; // 8.3KB
    __shared__ int edstS[32];
    __shared__ int offF_, offL_;

    const int tid = threadIdx.x;
    const int w = tid >> 6;
    const int lane = tid & 63;
    const int l15 = lane & 15;
    const int quad = lane >> 4;
    const int m0 = (w & 1) * 16;        // edge strip within tile
    const int nh = (w >> 1) * 32;       // feature half

    // GEMM1 weights in registers (32 VGPRs) — used 16x per tile.
    f16x8 wb1[4][2];
#pragma unroll
    for (int kt = 0; kt < 4; ++kt)
#pragma unroll
        for (int nf = 0; nf < 2; ++nf) {
            int n = nh + nf * 16 + l15;
#pragma unroll
            for (int j = 0; j < 8; ++j)
                wb1[kt][nf][j] = (f16)We1[(kt * 32 + quad * 8 + j) * 64 + n];
        }
    // GEMM2 weights in LDS (saves 16 regs; 4 extra b128 reads/tile).
    {
        int n = tid & 63;
        int kb2 = (tid >> 6) * 16;
        for (int kk = 0; kk < 16; ++kk) {
            int k = kb2 + kk;
            W2s[sw6(n, k)] = (f16)We2[k * 64 + n];
        }
    }

    const float b1v0 = be1[nh + l15], b1v1 = be1[nh + 16 + l15];
    const float b2v0 = be2[nh + l15], b2v1 = be2[nh + 16 + l15];

    const int i = tid >> 3;   // staging: edge in tile
    const int c = tid & 7;    // staging: 8-feature chunk

    // prologue: prefetch tile0 (edge idx + src row only)
    int2 pe;
    float4 pf0, pf1;
    {
        int ei = min(blockIdx.x * 32 + i, E - 1);
        pe = eix[ei];
        const float* ps = x + (size_t)pe.x * D + c * 8;
        pf0 = *(const float4*)ps;
        pf1 = *(const float4*)(ps + 4);
    }

    for (int tile = blockIdx.x; tile < T; tile += gridDim.x) {
        const int e0 = tile * 32;
        const int etile = min(32, E - e0);

        // ---- stage A: src from prefetch regs, dst loaded here (L1-hot) ----
        {
            const float* pd = x + (size_t)pe.y * D + c * 8;
            float4 da = *(const float4*)pd;
            float4 db = *(const float4*)(pd + 4);
            float sv[8] = {pf0.x, pf0.y, pf0.z, pf0.w, pf1.x, pf1.y, pf1.z, pf1.w};
            float dv[8] = {da.x, da.y, da.z, da.w, db.x, db.y, db.z, db.w};
            f16x8 sh, sl, dh, dl;
#pragma unroll
            for (int r = 0; r < 8; ++r) {
                sh[r] = (f16)sv[r]; sl[r] = (f16)(sv[r] - (float)sh[r]);
                dh[r] = (f16)dv[r]; dl[r] = (f16)(dv[r] - (float)dh[r]);
            }
            *(f16x8*)&Ahi[sw7(i, c * 8)] = sh;
            *(f16x8*)&Alo[sw7(i, c * 8)] = sl;
            *(f16x8*)&Ahi[sw7(i, 64 + c * 8)] = dh;
            *(f16x8*)&Alo[sw7(i, 64 + c * 8)] = dl;
            if (c == 0) edstS[i] = (e0 + i < E) ? pe.y : N;
            if (tid == 0)   offF_ = off[pe.y];
            if (tid == 248) offL_ = off[pe.y + 1];
        }
        __syncthreads();  // (1)

        // ---- prefetch next tile's edge idx + src row ----
        {
            int tn = tile + gridDim.x;
            if (tn < T) {
                int ei = min(tn * 32 + i, E - 1);
                pe = eix[ei];
                const float* ps = x + (size_t)pe.x * D + c * 8;
                pf0 = *(const float4*)ps;
                pf1 = *(const float4*)(ps + 4);
            }
        }

        f32x4 c0 = {0.f, 0.f, 0.f, 0.f}, c1 = {0.f, 0.f, 0.f, 0.f};
#pragma unroll
        for (int kt = 0; kt < 4; ++kt) {
            int k = kt * 32 + quad * 8;
            f16x8 ah = *(const f16x8*)&Ahi[sw7(m0 + l15, k)];
            f16x8 al = *(const f16x8*)&Alo[sw7(m0 + l15, k)];
            c0 = __builtin_amdgcn_mfma_f32_16x16x32_f16(ah, wb1[kt][0], c0, 0, 0, 0);
            c0 = __builtin_amdgcn_mfma_f32_16x16x32_f16(al, wb1[kt][0], c0, 0, 0, 0);
            c1 = __builtin_amdgcn_mfma_f32_16x16x32_f16(ah, wb1[kt][1], c1, 0, 0, 0);
            c1 = __builtin_amdgcn_mfma_f32_16x16x32_f16(al, wb1[kt][1], c1, 0, 0, 0);
        }

#pragma unroll
        for (int i2 = 0; i2 < 4; ++i2) {
            int m = m0 + quad * 4 + i2;
            Hbuf[sw6(m, nh + l15)]      = (f16)fmaxf(c0[i2] + b1v0, 0.f);
            Hbuf[sw6(m, nh + 16 + l15)] = (f16)fmaxf(c1[i2] + b1v1, 0.f);
        }
        __syncthreads();  // (2)

        f32x4 d0 = {0.f, 0.f, 0.f, 0.f}, d1 = {0.f, 0.f, 0.f, 0.f};
#pragma unroll
        for (int kt = 0; kt < 2; ++kt) {
            int k = kt * 32 + quad * 8;
            f16x8 ah = *(const f16x8*)&Hbuf[sw6(m0 + l15, k)];
            f16x8 b0 = *(const f16x8*)&W2s[sw6(nh + l15, k)];
            f16x8 b1 = *(const f16x8*)&W2s[sw6(nh + 16 + l15, k)];
            d0 = __builtin_amdgcn_mfma_f32_16x16x32_f16(ah, b0, d0, 0, 0, 0);
            d1 = __builtin_amdgcn_mfma_f32_16x16x32_f16(ah, b1, d1, 0, 0, 0);
        }

#pragma unroll
        for (int i2 = 0; i2 < 4; ++i2) {
            int m = m0 + quad * 4 + i2;
            float xs0 = (float)Ahi[sw7(m, nh + l15)] + (float)Alo[sw7(m, nh + l15)];
            float xs1 = (float)Ahi[sw7(m, nh + 16 + l15)] + (float)Alo[sw7(m, nh + 16 + l15)];
            Contrib[m * 65 + nh + l15]      = (d0[i2] + b2v0) * xs0;
            Contrib[m * 65 + nh + 16 + l15] = (d1[i2] + b2v1) * xs1;
        }
        __syncthreads();  // (3)

        if (tid < 64) {
            int j = tid;
            float a = 0.f;
            int cur = edstS[0];
            int runStart = 0;
#pragma unroll
            for (int ii = 0; ii < 32; ++ii) {
                a += Contrib[ii * 65 + j];
                int nxt = (ii < 31) ? edstS[ii + 1] : -1;
                if (nxt != cur) {
                    bool isLast = (ii == 31) || (nxt >= N);
                    bool complete = (runStart > 0 || offF_ == e0) &&
                                    (!isLast || offL_ == e0 + etile);
                    if (complete) hneigh[(size_t)cur * D + j] = a;
                    else atomicAdd(&hneigh[(size_t)cur * D + j], a);
                    a = 0.f; cur = nxt; runStart = ii + 1;
                }
            }
        }
        __syncthreads();  // (4)
    }
}

// ---------------------------------------------------------------------------
// Node MLP via MFMA, weights in VGPR fragments, 2-term split.
// ---------------------------------------------------------------------------
__global__ __launch_bounds__(256, 4) void node_mfma_kernel(
    float* __restrict__ h,
    const float* __restrict__ Wn, const float* __restrict__ bn,
    const float* __restrict__ Wg, const float* __restrict__ bg,
    float* __restrict__ gate, int N, int T)
{
    __shared__ __attribute__((aligned(16))) f16 ANhi[64 * 64];
    __shared__ __attribute__((aligned(16))) f16 ANlo[64 * 64];

    const int tid = threadIdx.x;
    const int w = tid >> 6;
    const int lane = tid & 63;
    const int l15 = lane & 15;
    const int quad = lane >> 4;
    const int m0 = w * 16;

    f16x8 wn[2][4];
#pragma unroll
    for (int kt = 0; kt < 2; ++kt)
#pragma unroll
        for (int nf = 0; nf < 4; ++nf) {
            int n = nf * 16 + l15;
#pragma unroll
            for (int j = 0; j < 8; ++j)
                wn[kt][nf][j] = (f16)Wn[(kt * 32 + quad * 8 + j) * 64 + n];
        }

    float bnv[4], wgv[4];
#pragma unroll
    for (int nt = 0; nt < 4; ++nt) {
        bnv[nt] = bn[nt * 16 + l15];
        wgv[nt] = Wg[nt * 16 + l15];
    }
    const float bgv = bg[0];

    for (int tile = blockIdx.x; tile < T; tile += gridDim.x) {
        const int t0 = tile * 64;

        {
            int i = tid >> 2;
            int q = tid & 3;
            int node = min(t0 + i, N - 1);
            const float* p = h + (size_t)node * D + q * 16;
#pragma unroll
            for (int r = 0; r < 4; ++r) {
                float4 v = *(const float4*)(p + r * 4);
                int k = q * 16 + r * 4;
                f16x4 hv, lv;
                hv[0] = (f16)v.x; lv[0] = (f16)(v.x - (float)hv[0]);
                hv[1] = (f16)v.y; lv[1] = (f16)(v.y - (float)hv[1]);
                hv[2] = (f16)v.z; lv[2] = (f16)(v.z - (float)hv[2]);
                hv[3] = (f16)v.w; lv[3] = (f16)(v.w - (float)hv[3]);
                *(f16x4*)&ANhi[sw6(i, k)] = hv;
                *(f16x4*)&ANlo[sw6(i, k)] = lv;
            }
        }
        __syncthreads();

        f32x4 cacc[4] = {{0.f,0.f,0.f,0.f},{0.f,0.f,0.f,0.f},{0.f,0.f,0.f,0.f},{0.f,0.f,0.f,0.f}};
#pragma unroll
        for (int kt = 0; kt < 2; ++kt) {
            int k = kt * 32 + quad * 8;
            f16x8 ah = *(const f16x8*)&ANhi[sw6(m0 + l15, k)];
            f16x8 al = *(const f16x8*)&ANlo[sw6(m0 + l15, k)];
#pragma unroll
            for (int nf = 0; nf < 4; ++nf) {
                cacc[nf] = __builtin_amdgcn_mfma_f32_16x16x32_f16(ah, wn[kt][nf], cacc[nf], 0, 0, 0);
                cacc[nf] = __builtin_amdgcn_mfma_f32_16x16x32_f16(al, wn[kt][nf], cacc[nf], 0, 0, 0);
            }
        }
        __syncthreads();

        float gpart[4] = {0.f, 0.f, 0.f, 0.f};
#pragma unroll
        for (int nt = 0; nt < 4; ++nt) {
            int n = nt * 16 + l15;
#pragma unroll
            for (int i2 = 0; i2 < 4; ++i2) {
                int m = t0 + m0 + quad * 4 + i2;
                float v = fmaxf(cacc[nt][i2] + bnv[nt], 0.f);
                if (m < N) h[(size_t)m * D + n] = v;
                gpart[i2] += v * wgv[nt];
            }
        }
#pragma unroll
        for (int s = 1; s < 16; s <<= 1) {
#pragma unroll
            for (int i2 = 0; i2 < 4; ++i2) gpart[i2] += __shfl_xor(gpart[i2], s);
        }
        if (l15 == 0) {
#pragma unroll
            for (int i2 = 0; i2 < 4; ++i2) {
                int m = t0 + m0 + quad * 4 + i2;
                if (m < N) gate[m] = gpart[i2] + bgv;
            }
        }
    }
}

// ---------------------------------------------------------------------------
// Pool: one block per graph; softmax over gates, weighted sum, classifier.
// ---------------------------------------------------------------------------
__global__ __launch_bounds__(256) void pool_kernel(
    const float* __restrict__ h2,
    const float* __restrict__ gate,
    const int* __restrict__ gid,
    const float* __restrict__ Wfc, const float* __restrict__ bfc,
    float* __restrict__ out, int N, int C)
{
    int g = blockIdx.x;
    int tid = threadIdx.x;

    int lo = 0, hi = N;
    while (lo < hi) { int mid = (lo + hi) >> 1; if (gid[mid] < g) lo = mid + 1; else hi = mid; }
    int s = lo;
    hi = N;
    while (lo < hi) { int mid = (lo + hi) >> 1; if (gid[mid] < g + 1) lo = mid + 1; else hi = mid; }
    int e = lo;

    __shared__ float red[256];
    __shared__ float accs[4][D];
    __shared__ float dens[4];

    float m = -INFINITY;
    for (int i = s + tid; i < e; i += 256) m = fmaxf(m, gate[i]);
    red[tid] = m;
    __syncthreads();
    for (int w = 128; w > 0; w >>= 1) {
        if (tid < w) red[tid] = fmaxf(red[tid], red[tid + w]);
        __syncthreads();
    }
    float gmax = red[0];
    __syncthreads();

    int f = tid & (D - 1);
    int grp = tid >> 6;
    float acc = 0.0f, den = 0.0f;
    for (int i = s + grp; i < e; i += 4) {
        float w = expf(gate[i] - gmax);
        acc += w * h2[(size_t)i * D + f];
        if (f == 0) den += w;
    }
    accs[grp][f] = acc;
    if (f == 0) dens[grp] = den;
    __syncthreads();

    if (tid < D) {
        float p = accs[0][tid] + accs[1][tid] + accs[2][tid] + accs[3][tid];
        float dn = dens[0] + dens[1] + dens[2] + dens[3];
        p = (e > s) ? (p / dn) : 0.0f;
        red[tid] = p;
    }
    __syncthreads();

    if (tid < C) {
        float o = bfc[tid];
#pragma unroll
        for (int k = 0; k < D; ++k) o += red[k] * Wfc[k * C + tid];
        out[g * C + tid] = o;
    }
}

extern "C" void kernel_launch(void* const* d_in, const int* in_sizes, int n_in,
                              void* d_out, int out_size, void* d_ws, size_t ws_size,
                              hipStream_t stream) {
    const float* x   = (const float*)d_in[0];
    const float* We1 = (const float*)d_in[1];
    const float* be1 = (const float*)d_in[2];
    const float* We2 = (const float*)d_in[3];
    const float* be2 = (const float*)d_in[4];
    const float* Wn  = (const float*)d_in[5];
    const float* bn  = (const float*)d_in[6];
    const float* Wg  = (const float*)d_in[7];
    const float* bg  = (const float*)d_in[8];
    const float* Wfc = (const float*)d_in[9];
    const float* bfc = (const float*)d_in[10];
    const int* src = (const int*)d_in[11];
    const int* dst = (const int*)d_in[12];
    const int* gid = (const int*)d_in[13];

    const int N = in_sizes[0] / D;
    const int E = in_sizes[11];
    const int C = 10;
    const int G = out_size / C;
    const int NB = (N + BNODES - 1) / BNODES;

    // workspace: eix2 | union{eixA, hneigh} | gate | off | bucket arrays
    int2*  eix2   = (int2*)d_ws;                          // [E]      12.8MB
    int2*  eixA   = eix2 + E;                             // [E]      12.8MB
    float* hneigh = (float*)eixA;                         // [(N+1)*64] 25.6MB (overlay)
    float* gate   = hneigh + (size_t)(N + 1) * D;         // [N]
    int*   off    = (int*)(gate + N);                     // [N+1]
    int*   bhist  = off + N + 1;                          // [NB]
    int*   boff   = bhist + NB;                           // [NB+1]
    int*   bcursor= boff + NB + 1;                        // [NB]
    float* outp   = (float*)d_out;

    const int Bh = (E + EB - 1) / EB;
    const int Te = (E + 31) / 32;
    const int Tn = (N + 63) / 64;

    hipMemsetAsync(bhist, 0, (size_t)NB * sizeof(int), stream);

    bucket_hist<<<Bh, 256, 0, stream>>>(dst, bhist, E, NB);
    bucket_scan<<<1, 256, 0, stream>>>(bhist, boff, bcursor, NB);
    bucket_fill<<<Bh, 256, 0, stream>>>(dst, src, bcursor, eixA, E, NB);
    bucket_sort<<<NB, 256, 0, stream>>>(eixA, boff, eix2, off, N, NB);

    // eixA dead; zero hneigh (overlay) before edge kernel
    hipMemsetAsync(hneigh, 0, (size_t)(N + 1) * D * sizeof(float), stream);

    edge_mfma_kernel<<<1024, 256, 0, stream>>>(x, We1, be1, We2, be2,
                                               off, eix2, hneigh, N, E, Te);
    node_mfma_kernel<<<1024, 256, 0, stream>>>(hneigh, Wn, bn, Wg, bg, gate, N, Tn);
    pool_kernel<<<G, 256, 0, stream>>>(hneigh, gate, gid, Wfc, bfc, outp, N, C);
}

// Round 12
// 430.225 us; speedup vs baseline: 1.8973x; 1.0511x over previous
//
#include <hip/hip_runtime.h>
#include <hip/hip_bf16.h>

#define D 64
#define BSH 6            // log2(nodes per bucket)
#define BNODES 64
#define NBMAX 2048       // LDS hist capacity (N <= 131072)
#define EB 4096          // edges per hist/fill block

typedef _Float16 f16;
typedef _Float16 f16x4 __attribute__((ext_vector_type(4)));
typedef _Float16 f16x8 __attribute__((ext_vector_type(8)));
typedef float f32x4 __attribute__((ext_vector_type(4)));

__device__ __forceinline__ int sw7(int m, int k) {  // row stride 128 f16
    return (m << 7) + (((k >> 3) ^ (m & 7)) << 3) + (k & 7);
}
__device__ __forceinline__ int sw6(int m, int k) {  // row stride 64 f16
    return (m << 6) + ((((k >> 3) ^ (m & 7)) & 7) << 3) + (k & 7);
}

// ---------------------------------------------------------------------------
// Bucket partition (coarse sort by dst>>6) — two-level LDS histograms.
// ---------------------------------------------------------------------------
__global__ __launch_bounds__(256) void bucket_hist(
    const int* __restrict__ dst, int* __restrict__ bhist, int E, int NB)
{
    __shared__ int lhist[NBMAX];
    int tid = threadIdx.x;
    for (int b = tid; b < NB; b += 256) lhist[b] = 0;
    __syncthreads();
    int base = blockIdx.x * EB;
#pragma unroll
    for (int r = 0; r < EB / 256; ++r) {
        int e = base + r * 256 + tid;
        if (e < E) atomicAdd(&lhist[dst[e] >> BSH], 1);
    }
    __syncthreads();
    for (int b = tid; b < NB; b += 256) {
        int v = lhist[b];
        if (v) atomicAdd(&bhist[b], v);
    }
}

__global__ __launch_bounds__(256) void bucket_scan(
    const int* __restrict__ bhist, int* __restrict__ boff,
    int* __restrict__ bcursor, int NB)
{
    __shared__ int lds[256];
    int tid = threadIdx.x;
    int chunk = (NB + 255) / 256;
    int b0 = tid * chunk;
    int b1 = min(b0 + chunk, NB);
    int s = 0;
    for (int b = b0; b < b1; ++b) s += bhist[b];
    lds[tid] = s;
    __syncthreads();
    for (int d2 = 1; d2 < 256; d2 <<= 1) {
        int v = (tid >= d2) ? lds[tid - d2] : 0;
        __syncthreads();
        lds[tid] += v;
        __syncthreads();
    }
    int run = (tid == 0) ? 0 : lds[tid - 1];
    for (int b = b0; b < b1; ++b) {
        boff[b] = run;
        bcursor[b] = run;
        run += bhist[b];
    }
    if (tid == 255) boff[NB] = lds[255];
}

__global__ __launch_bounds__(256) void bucket_fill(
    const int* __restrict__ dst, const int* __restrict__ src,
    int* __restrict__ bcursor, int2* __restrict__ eix, int E, int NB)
{
    __shared__ int lhist[NBMAX];
    __shared__ int lcur[NBMAX];
    int tid = threadIdx.x;
    for (int b = tid; b < NB; b += 256) lhist[b] = 0;
    __syncthreads();
    int base = blockIdx.x * EB;
    int dv[EB / 256];
#pragma unroll
    for (int r = 0; r < EB / 256; ++r) {
        int e = base + r * 256 + tid;
        dv[r] = (e < E) ? dst[e] : -1;
        if (dv[r] >= 0) atomicAdd(&lhist[dv[r] >> BSH], 1);
    }
    __syncthreads();
    for (int b = tid; b < NB; b += 256) {
        int v = lhist[b];
        lcur[b] = v ? atomicAdd(&bcursor[b], v) : 0;
    }
    __syncthreads();
#pragma unroll
    for (int r = 0; r < EB / 256; ++r) {
        int e = base + r * 256 + tid;
        if (dv[r] >= 0) {
            int p = atomicAdd(&lcur[dv[r] >> BSH], 1);
            eix[p] = make_int2(src[e], dv[r]);
        }
    }
}

// ---------------------------------------------------------------------------
// Per-bucket exact counting sort (64 bins in LDS) -> globally dst-sorted eix2.
// (off[] removed: edge kernel now tests run-completeness via neighbor dst.)
// ---------------------------------------------------------------------------
__global__ __launch_bounds__(256) void bucket_sort(
    const int2* __restrict__ eix, const int* __restrict__ boff,
    int2* __restrict__ eix2, int NB)
{
    __shared__ int h64[BNODES];
    __shared__ int cur64[BNODES];
    int bk = blockIdx.x;
    int s = boff[bk], e = boff[bk + 1];
    int tid = threadIdx.x;
    int nbase = bk << BSH;

    if (tid < BNODES) h64[tid] = 0;
    __syncthreads();
    for (int i = s + tid; i < e; i += 256)
        atomicAdd(&h64[eix[i].y - nbase], 1);
    __syncthreads();
    if (tid < BNODES) {
        int v = h64[tid];
        int inc = v;
        for (int d2 = 1; d2 < BNODES; d2 <<= 1) {   // wave-level inclusive scan
            int t = __shfl_up(inc, d2);
            if (tid >= d2) inc += t;
        }
        cur64[tid] = inc - v;                        // exclusive prefix
    }
    __syncthreads();
    for (int i = s + tid; i < e; i += 256) {
        int2 ed = eix[i];
        int slot = atomicAdd(&cur64[ed.y - nbase], 1);
        eix2[s + slot] = ed;
    }
}

// ---------------------------------------------------------------------------
// Edge MLP via MFMA. GEMM1 A = plain f16 (lo-term dropped: measured absmax
// headroom 5.3x pays for it); xs kept EXACT as f32 in LDS for u_mul_e.
// wb1 in VGPRs, We2 in LDS. Run-completeness via neighbor-dst test (no off[]).
// 4 blocks/CU (LDS ~37KB, unified regs ~110).
// ---------------------------------------------------------------------------
__global__ __launch_bounds__(256, 4) void edge_mfma_kernel(
    const float* __restrict__ x,
    const float* __restrict__ We1, const float* __restrict__ be1,
    const float* __restrict__ We2, const float* __restrict__ be2,
    const int2* __restrict__ eix,
    float* __restrict__ hneigh, int N, int E, int T)
{
    __shared__ __attribute__((aligned(16))) f16 Ahi[32 * 128];   // 8KB
    __shared__ __attribute__((aligned(16))) float Xs[32 * 68];   // 8.5KB (stride 68: 16B-aligned rows)
    __shared__ __attribute__((aligned(16))) f16 Hbuf[32 * 64];   // 4KB
    __shared__ __attribute__((aligned(16))) f16 W2s[64 * 64];    // 8KB
    __shared__ __attribute__((aligned(16))) float Contrib[32 * 65]; // 8.3KB
    __shared__ int edstS[32];
    __shared__ int prevD_, nextD_;

    const int tid = threadIdx.x;
    const int w = tid >> 6;
    const int lane = tid & 63;
    const int l15 = lane & 15;
    const int quad = lane >> 4;
    const int m0 = (w & 1) * 16;        // edge strip within tile
    const int nh = (w >> 1) * 32;       // feature half

    // GEMM1 weights in registers (32 VGPRs).
    f16x8 wb1[4][2];
#pragma unroll
    for (int kt = 0; kt < 4; ++kt)
#pragma unroll
        for (int nf = 0; nf < 2; ++nf) {
            int n = nh + nf * 16 + l15;
#pragma unroll
            for (int j = 0; j < 8; ++j)
                wb1[kt][nf][j] = (f16)We1[(kt * 32 + quad * 8 + j) * 64 + n];
        }
    // GEMM2 weights in LDS.
    {
        int n = tid & 63;
        int kb2 = (tid >> 6) * 16;
        for (int kk = 0; kk < 16; ++kk) {
            int k = kb2 + kk;
            W2s[sw6(n, k)] = (f16)We2[k * 64 + n];
        }
    }

    const float b1v0 = be1[nh + l15], b1v1 = be1[nh + 16 + l15];
    const float b2v0 = be2[nh + l15], b2v1 = be2[nh + 16 + l15];

    const int i = tid >> 3;   // staging: edge in tile
    const int c = tid & 7;    // staging: 8-feature chunk

    // prologue: prefetch tile0 (edge idx + src row)
    int2 pe;
    float4 pf0, pf1;
    {
        int ei = min(blockIdx.x * 32 + i, E - 1);
        pe = eix[ei];
        const float* ps = x + (size_t)pe.x * D + c * 8;
        pf0 = *(const float4*)ps;
        pf1 = *(const float4*)(ps + 4);
    }

    for (int tile = blockIdx.x; tile < T; tile += gridDim.x) {
        const int e0 = tile * 32;

        // ---- stage: src f16 + exact f32 (from prefetch), dst f16 (L1-hot) ----
        {
            const float* pd = x + (size_t)pe.y * D + c * 8;
            float4 da = *(const float4*)pd;
            float4 db = *(const float4*)(pd + 4);
            f16x8 sh, dh;
            sh[0] = (f16)pf0.x; sh[1] = (f16)pf0.y; sh[2] = (f16)pf0.z; sh[3] = (f16)pf0.w;
            sh[4] = (f16)pf1.x; sh[5] = (f16)pf1.y; sh[6] = (f16)pf1.z; sh[7] = (f16)pf1.w;
            dh[0] = (f16)da.x;  dh[1] = (f16)da.y;  dh[2] = (f16)da.z;  dh[3] = (f16)da.w;
            dh[4] = (f16)db.x;  dh[5] = (f16)db.y;  dh[6] = (f16)db.z;  dh[7] = (f16)db.w;
            *(f16x8*)&Ahi[sw7(i, c * 8)] = sh;
            *(f16x8*)&Ahi[sw7(i, 64 + c * 8)] = dh;
            *(float4*)&Xs[i * 68 + c * 8] = pf0;
            *(float4*)&Xs[i * 68 + c * 8 + 4] = pf1;
            if (c == 0) edstS[i] = (e0 + i < E) ? pe.y : N;
            if (tid == 0)  prevD_ = (e0 > 0) ? eix[e0 - 1].y : -2;
            if (tid == 64) nextD_ = (e0 + 32 < E) ? eix[e0 + 32].y : -2;
        }
        __syncthreads();  // (1)

        // ---- prefetch next tile's edge idx + src row ----
        {
            int tn = tile + gridDim.x;
            if (tn < T) {
                int ei = min(tn * 32 + i, E - 1);
                pe = eix[ei];
                const float* ps = x + (size_t)pe.x * D + c * 8;
                pf0 = *(const float4*)ps;
                pf1 = *(const float4*)(ps + 4);
            }
        }

        // ---- GEMM1: [32,128]@[128,64], A single f16 ----
        f32x4 c0 = {0.f, 0.f, 0.f, 0.f}, c1 = {0.f, 0.f, 0.f, 0.f};
#pragma unroll
        for (int kt = 0; kt < 4; ++kt) {
            int k = kt * 32 + quad * 8;
            f16x8 ah = *(const f16x8*)&Ahi[sw7(m0 + l15, k)];
            c0 = __builtin_amdgcn_mfma_f32_16x16x32_f16(ah, wb1[kt][0], c0, 0, 0, 0);
            c1 = __builtin_amdgcn_mfma_f32_16x16x32_f16(ah, wb1[kt][1], c1, 0, 0, 0);
        }

#pragma unroll
        for (int i2 = 0; i2 < 4; ++i2) {
            int m = m0 + quad * 4 + i2;
            Hbuf[sw6(m, nh + l15)]      = (f16)fmaxf(c0[i2] + b1v0, 0.f);
            Hbuf[sw6(m, nh + 16 + l15)] = (f16)fmaxf(c1[i2] + b1v1, 0.f);
        }
        __syncthreads();  // (2)

        // ---- GEMM2: [32,64]@[64,64] ----
        f32x4 d0 = {0.f, 0.f, 0.f, 0.f}, d1 = {0.f, 0.f, 0.f, 0.f};
#pragma unroll
        for (int kt = 0; kt < 2; ++kt) {
            int k = kt * 32 + quad * 8;
            f16x8 ah = *(const f16x8*)&Hbuf[sw6(m0 + l15, k)];
            f16x8 b0 = *(const f16x8*)&W2s[sw6(nh + l15, k)];
            f16x8 b1 = *(const f16x8*)&W2s[sw6(nh + 16 + l15, k)];
            d0 = __builtin_amdgcn_mfma_f32_16x16x32_f16(ah, b0, d0, 0, 0, 0);
            d1 = __builtin_amdgcn_mfma_f32_16x16x32_f16(ah, b1, d1, 0, 0, 0);
        }

        // ---- contrib = xs * (d + be2), xs exact f32 from LDS ----
#pragma unroll
        for (int i2 = 0; i2 < 4; ++i2) {
            int m = m0 + quad * 4 + i2;
            float xs0 = Xs[m * 68 + nh + l15];
            float xs1 = Xs[m * 68 + nh + 16 + l15];
            Contrib[m * 65 + nh + l15]      = (d0[i2] + b2v0) * xs0;
            Contrib[m * 65 + nh + 16 + l15] = (d1[i2] + b2v1) * xs1;
        }
        __syncthreads();  // (3)

        // ---- segmented sum over sorted dst runs ----
        if (tid < 64) {
            int j = tid;
            float a = 0.f;
            int cur = edstS[0];
            int runStart = 0;
#pragma unroll
            for (int ii = 0; ii < 32; ++ii) {
                a += Contrib[ii * 65 + j];
                int nxt = (ii < 31) ? edstS[ii + 1] : -3;
                if (nxt != cur) {
                    bool firstRun = (runStart == 0);
                    bool lastRun = (ii == 31) || (nxt >= N);
                    bool complete = (!firstRun || prevD_ != cur) &&
                                    (!lastRun || nextD_ != cur);
                    if (complete) hneigh[(size_t)cur * D + j] = a;
                    else atomicAdd(&hneigh[(size_t)cur * D + j], a);
                    a = 0.f; cur = nxt; runStart = ii + 1;
                }
            }
        }
        __syncthreads();  // (4)
    }
}

// ---------------------------------------------------------------------------
// Node MLP via MFMA, weights in VGPR fragments, 2-term split (unchanged —
// keeps precision budget concentrated on the edge-kernel change).
// ---------------------------------------------------------------------------
__global__ __launch_bounds__(256, 4) void node_mfma_kernel(
    float* __restrict__ h,
    const float* __restrict__ Wn, const float* __restrict__ bn,
    const float* __restrict__ Wg, const float* __restrict__ bg,
    float* __restrict__ gate, int N, int T)
{
    __shared__ __attribute__((aligned(16))) f16 ANhi[64 * 64];
    __shared__ __attribute__((aligned(16))) f16 ANlo[64 * 64];

    const int tid = threadIdx.x;
    const int w = tid >> 6;
    const int lane = tid & 63;
    const int l15 = lane & 15;
    const int quad = lane >> 4;
    const int m0 = w * 16;

    f16x8 wn[2][4];
#pragma unroll
    for (int kt = 0; kt < 2; ++kt)
#pragma unroll
        for (int nf = 0; nf < 4; ++nf) {
            int n = nf * 16 + l15;
#pragma unroll
            for (int j = 0; j < 8; ++j)
                wn[kt][nf][j] = (f16)Wn[(kt * 32 + quad * 8 + j) * 64 + n];
        }

    float bnv[4], wgv[4];
#pragma unroll
    for (int nt = 0; nt < 4; ++nt) {
        bnv[nt] = bn[nt * 16 + l15];
        wgv[nt] = Wg[nt * 16 + l15];
    }
    const float bgv = bg[0];

    for (int tile = blockIdx.x; tile < T; tile += gridDim.x) {
        const int t0 = tile * 64;

        {
            int i = tid >> 2;
            int q = tid & 3;
            int node = min(t0 + i, N - 1);
            const float* p = h + (size_t)node * D + q * 16;
#pragma unroll
            for (int r = 0; r < 4; ++r) {
                float4 v = *(const float4*)(p + r * 4);
                int k = q * 16 + r * 4;
                f16x4 hv, lv;
                hv[0] = (f16)v.x; lv[0] = (f16)(v.x - (float)hv[0]);
                hv[1] = (f16)v.y; lv[1] = (f16)(v.y - (float)hv[1]);
                hv[2] = (f16)v.z; lv[2] = (f16)(v.z - (float)hv[2]);
                hv[3] = (f16)v.w; lv[3] = (f16)(v.w - (float)hv[3]);
                *(f16x4*)&ANhi[sw6(i, k)] = hv;
                *(f16x4*)&ANlo[sw6(i, k)] = lv;
            }
        }
        __syncthreads();

        f32x4 cacc[4] = {{0.f,0.f,0.f,0.f},{0.f,0.f,0.f,0.f},{0.f,0.f,0.f,0.f},{0.f,0.f,0.f,0.f}};
#pragma unroll
        for (int kt = 0; kt < 2; ++kt) {
            int k = kt * 32 + quad * 8;
            f16x8 ah = *(const f16x8*)&ANhi[sw6(m0 + l15, k)];
            f16x8 al = *(const f16x8*)&ANlo[sw6(m0 + l15, k)];
#pragma unroll
            for (int nf = 0; nf < 4; ++nf) {
                cacc[nf] = __builtin_amdgcn_mfma_f32_16x16x32_f16(ah, wn[kt][nf], cacc[nf], 0, 0, 0);
                cacc[nf] = __builtin_amdgcn_mfma_f32_16x16x32_f16(al, wn[kt][nf], cacc[nf], 0, 0, 0);
            }
        }
        __syncthreads();

        float gpart[4] = {0.f, 0.f, 0.f, 0.f};
#pragma unroll
        for (int nt = 0; nt < 4; ++nt) {
            int n = nt * 16 + l15;
#pragma unroll
            for (int i2 = 0; i2 < 4; ++i2) {
                int m = t0 + m0 + quad * 4 + i2;
                float v = fmaxf(cacc[nt][i2] + bnv[nt], 0.f);
                if (m < N) h[(size_t)m * D + n] = v;
                gpart[i2] += v * wgv[nt];
            }
        }
#pragma unroll
        for (int s = 1; s < 16; s <<= 1) {
#pragma unroll
            for (int i2 = 0; i2 < 4; ++i2) gpart[i2] += __shfl_xor(gpart[i2], s);
        }
        if (l15 == 0) {
#pragma unroll
            for (int i2 = 0; i2 < 4; ++i2) {
                int m = t0 + m0 + quad * 4 + i2;
                if (m < N) gate[m] = gpart[i2] + bgv;
            }
        }
    }
}

// ---------------------------------------------------------------------------
// Pool: one block per graph; softmax over gates, weighted sum, classifier.
// ---------------------------------------------------------------------------
__global__ __launch_bounds__(256) void pool_kernel(
    const float* __restrict__ h2,
    const float* __restrict__ gate,
    const int* __restrict__ gid,
    const float* __restrict__ Wfc, const float* __restrict__ bfc,
    float* __restrict__ out, int N, int C)
{
    int g = blockIdx.x;
    int tid = threadIdx.x;

    int lo = 0, hi = N;
    while (lo < hi) { int mid = (lo + hi) >> 1; if (gid[mid] < g) lo = mid + 1; else hi = mid; }
    int s = lo;
    hi = N;
    while (lo < hi) { int mid = (lo + hi) >> 1; if (gid[mid] < g + 1) lo = mid + 1; else hi = mid; }
    int e = lo;

    __shared__ float red[256];
    __shared__ float accs[4][D];
    __shared__ float dens[4];

    float m = -INFINITY;
    for (int i = s + tid; i < e; i += 256) m = fmaxf(m, gate[i]);
    red[tid] = m;
    __syncthreads();
    for (int w = 128; w > 0; w >>= 1) {
        if (tid < w) red[tid] = fmaxf(red[tid], red[tid + w]);
        __syncthreads();
    }
    float gmax = red[0];
    __syncthreads();

    int f = tid & (D - 1);
    int grp = tid >> 6;
    float acc = 0.0f, den = 0.0f;
    for (int i = s + grp; i < e; i += 4) {
        float w = expf(gate[i] - gmax);
        acc += w * h2[(size_t)i * D + f];
        if (f == 0) den += w;
    }
    accs[grp][f] = acc;
    if (f == 0) dens[grp] = den;
    __syncthreads();

    if (tid < D) {
        float p = accs[0][tid] + accs[1][tid] + accs[2][tid] + accs[3][tid];
        float dn = dens[0] + dens[1] + dens[2] + dens[3];
        p = (e > s) ? (p / dn) : 0.0f;
        red[tid] = p;
    }
    __syncthreads();

    if (tid < C) {
        float o = bfc[tid];
#pragma unroll
        for (int k = 0; k < D; ++k) o += red[k] * Wfc[k * C + tid];
        out[g * C + tid] = o;
    }
}

extern "C" void kernel_launch(void* const* d_in, const int* in_sizes, int n_in,
                              void* d_out, int out_size, void* d_ws, size_t ws_size,
                              hipStream_t stream) {
    const float* x   = (const float*)d_in[0];
    const float* We1 = (const float*)d_in[1];
    const float* be1 = (const float*)d_in[2];
    const float* We2 = (const float*)d_in[3];
    const float* be2 = (const float*)d_in[4];
    const float* Wn  = (const float*)d_in[5];
    const float* bn  = (const float*)d_in[6];
    const float* Wg  = (const float*)d_in[7];
    const float* bg  = (const float*)d_in[8];
    const float* Wfc = (const float*)d_in[9];
    const float* bfc = (const float*)d_in[10];
    const int* src = (const int*)d_in[11];
    const int* dst = (const int*)d_in[12];
    const int* gid = (const int*)d_in[13];

    const int N = in_sizes[0] / D;
    const int E = in_sizes[11];
    const int C = 10;
    const int G = out_size / C;
    const int NB = (N + BNODES - 1) / BNODES;

    // workspace: eix2 | union{eixA, hneigh} | gate | bucket arrays
    int2*  eix2   = (int2*)d_ws;                          // [E]      12.8MB
    int2*  eixA   = eix2 + E;                             // [E]      12.8MB
    float* hneigh = (float*)eixA;                         // [(N+1)*64] 25.6MB (overlay)
    float* gate   = hneigh + (size_t)(N + 1) * D;         // [N]
    int*   bhist  = (int*)(gate + N);                     // [NB]
    int*   boff   = bhist + NB;                           // [NB+1]
    int*   bcursor= boff + NB + 1;                        // [NB]
    float* outp   = (float*)d_out;

    const int Bh = (E + EB - 1) / EB;
    const int Te = (E + 31) / 32;
    const int Tn = (N + 63) / 64;

    hipMemsetAsync(bhist, 0, (size_t)NB * sizeof(int), stream);

    bucket_hist<<<Bh, 256, 0, stream>>>(dst, bhist, E, NB);
    bucket_scan<<<1, 256, 0, stream>>>(bhist, boff, bcursor, NB);
    bucket_fill<<<Bh, 256, 0, stream>>>(dst, src, bcursor, eixA, E, NB);
    bucket_sort<<<NB, 256, 0, stream>>>(eixA, boff, eix2, NB);

    // eixA dead; zero hneigh (overlay) before edge kernel
    hipMemsetAsync(hneigh, 0, (size_t)(N + 1) * D * sizeof(float), stream);

    edge_mfma_kernel<<<1024, 256, 0, stream>>>(x, We1, be1, We2, be2,
                                               eix2, hneigh, N, E, Te);
    node_mfma_kernel<<<1024, 256, 0, stream>>>(hneigh, Wn, bn, Wg, bg, gate, N, Tn);
    pool_kernel<<<G, 256, 0, stream>>>(hneigh, gate, gid, Wfc, bfc, outp, N, C);
}